// Round 1
// baseline (9798.736 us; speedup 1.0000x reference)
//
#include <hip/hip_runtime.h>

// GRU: B=64, T=2048, D=256, U=256.
// Plan:
//  k0: transpose kernel(256x768 f32) -> Wt(768x256 bf16), recurrent -> Ut(768x256 bf16)
//  k1: x_proj = x @ kernel + bias  (bf16 MFMA, fp32 out in ws if it fits, else bf16)
//  k2: recurrence, 4 blocks x 512 thr, one block = 16 batches on one CU,
//      U resident in VGPRs as MFMA B-fragments, h in LDS (fragment-order, conflict-free).

#define TB 2048
#define NU 256
#define G3 768

typedef __attribute__((ext_vector_type(8))) short bf16x8;
typedef __attribute__((ext_vector_type(4))) float f32x4;

__device__ inline unsigned short f2bf(float f){
  union{float f; unsigned u;} v; v.f = f;
  unsigned r = v.u + 0x7fffu + ((v.u >> 16) & 1u);   // RNE
  return (unsigned short)(r >> 16);
}
__device__ inline float bf2f(unsigned short u){
  union{unsigned u; float f;} v; v.u = ((unsigned)u) << 16; return v.f;
}
__device__ inline unsigned pk2(float a, float b){
  return (unsigned)f2bf(a) | ((unsigned)f2bf(b) << 16);
}

// ---------------- k0: weight transpose to bf16 [col][k] ----------------
__global__ __launch_bounds__(256) void transpose_k(const float* __restrict__ W,
                                                   const float* __restrict__ R,
                                                   unsigned short* __restrict__ Wt,
                                                   unsigned short* __restrict__ Ut){
  int n = blockIdx.x;        // 0..1535
  int k = threadIdx.x;       // 0..255
  if (n < G3) Wt[n*NU + k] = f2bf(W[k*G3 + n]);
  else        Ut[(n-G3)*NU + k] = f2bf(R[k*G3 + (n-G3)]);
}

// ---------------- k1: projection GEMM  (M=131072, K=256, N=768) ----------------
// 64x64 tile / block, 4 waves each 32x32 (2x2 mfma 16x16x32), K chunked by 64.
// LDS in fragment-contiguous order: [kc32][q][row][8] so frag read = base + lane*16.
template<int F32OUT>
__global__ __launch_bounds__(256) void proj_k(const float* __restrict__ x,
                                              const unsigned short* __restrict__ Wt,
                                              const float* __restrict__ bias,
                                              void* __restrict__ xproj){
  __shared__ short As[4096];
  __shared__ short Bs[4096];
  const int tid  = threadIdx.x;
  const int lane = tid & 63;
  const int wv   = tid >> 6;
  const int wr   = wv >> 1, wc = wv & 1;
  const int q    = lane >> 4, r16 = lane & 15;
  const int bm   = blockIdx.x, bn = blockIdx.y;

  f32x4 acc[2][2];
  #pragma unroll
  for (int a=0;a<2;a++)
    #pragma unroll
    for (int b=0;b<2;b++) acc[a][b] = {0.f,0.f,0.f,0.f};

  const int mA = tid >> 2, kq = tid & 3;
  const int kc32 = kq >> 1, q0 = (kq & 1) * 2;

  for (int kc0 = 0; kc0 < 256; kc0 += 64){
    // stage A (x fp32 -> bf16)
    {
      const float* src = x + (size_t)(bm*64 + mA)*256 + kc0 + kq*16;
      float4 f0 = *(const float4*)(src);
      float4 f1 = *(const float4*)(src+4);
      float4 f2 = *(const float4*)(src+8);
      float4 f3 = *(const float4*)(src+12);
      *(uint2*)&As[kc32*2048 + q0*512     + mA*8 + 0] = make_uint2(pk2(f0.x,f0.y), pk2(f0.z,f0.w));
      *(uint2*)&As[kc32*2048 + q0*512     + mA*8 + 4] = make_uint2(pk2(f1.x,f1.y), pk2(f1.z,f1.w));
      *(uint2*)&As[kc32*2048 + (q0+1)*512 + mA*8 + 0] = make_uint2(pk2(f2.x,f2.y), pk2(f2.z,f2.w));
      *(uint2*)&As[kc32*2048 + (q0+1)*512 + mA*8 + 4] = make_uint2(pk2(f3.x,f3.y), pk2(f3.z,f3.w));
    }
    // stage B (Wt bf16, already [col][k])
    {
      const unsigned short* srcB = Wt + (size_t)(bn*64 + mA)*256 + kc0 + kq*16;
      uint4 b0v = *(const uint4*)(srcB);
      uint4 b1v = *(const uint4*)(srcB+8);
      *(uint4*)&Bs[kc32*2048 + q0*512     + mA*8] = b0v;
      *(uint4*)&Bs[kc32*2048 + (q0+1)*512 + mA*8] = b1v;
    }
    __syncthreads();
    #pragma unroll
    for (int kk = 0; kk < 2; kk++){
      bf16x8 av[2], bv[2];
      #pragma unroll
      for (int rt=0; rt<2; rt++)
        av[rt] = *(const bf16x8*)&As[kk*2048 + q*512 + (wr*32+rt*16+r16)*8];
      #pragma unroll
      for (int ct=0; ct<2; ct++)
        bv[ct] = *(const bf16x8*)&Bs[kk*2048 + q*512 + (wc*32+ct*16+r16)*8];
      #pragma unroll
      for (int rt=0; rt<2; rt++)
        #pragma unroll
        for (int ct=0; ct<2; ct++)
          acc[rt][ct] = __builtin_amdgcn_mfma_f32_16x16x32_bf16(av[rt], bv[ct], acc[rt][ct], 0,0,0);
    }
    __syncthreads();
  }
  // epilogue: + bias, store
  #pragma unroll
  for (int rt=0; rt<2; rt++){
    #pragma unroll
    for (int ct=0; ct<2; ct++){
      int colg = bn*64 + wc*32 + ct*16 + r16;
      float bb = bias[colg];
      #pragma unroll
      for (int i=0;i<4;i++){
        int rowg = bm*64 + wr*32 + rt*16 + q*4 + i;
        float v = acc[rt][ct][i] + bb;
        if (F32OUT) ((float*)xproj)[(size_t)rowg*768 + colg] = v;
        else ((unsigned short*)xproj)[(size_t)rowg*768 + colg] = f2bf(v);
      }
    }
  }
}

// ---------------- k2: recurrence ----------------
// 4 blocks x 512 threads (8 waves). Block g owns batches g*16..g*16+15.
// Wave w owns z/r col-tiles {4w..4w+3} (gate cols) and h col-tiles {2w,2w+1}.
// U fragments live in registers (48 x bf16x8 per thread = 192 VGPRs).
template<int F32XP>
__global__ __launch_bounds__(512, 1) void gru_k(const void* __restrict__ xproj_v,
                                                const unsigned short* __restrict__ Ut,
                                                float* __restrict__ out){
  __shared__ short h_fb[4096];      // h bf16, fragment-order [kc][q][row][8]
  __shared__ short v_fb[4096];      // (r*h) bf16, same order
  __shared__ float z_ls[16*257];    // z gate fp32
  __shared__ float h32 [16*257];    // h fp32 master

  const int tid  = threadIdx.x;
  const int w    = tid >> 6;        // wave 0..7
  const int lane = tid & 63;
  const int q    = lane >> 4, r16 = lane & 15;
  const int b0   = blockIdx.x * 16;

  const float*          xpf = (const float*)xproj_v;
  const unsigned short* xph = (const unsigned short*)xproj_v;

  for (int i = tid; i < 4096;   i += 512) h_fb[i] = 0;
  for (int i = tid; i < 16*257; i += 512) h32[i]  = 0.f;

  // load U fragments into registers (one-time)
  bf16x8 Uzr[4][8];
  bf16x8 Uhh[2][8];
  #pragma unroll
  for (int tt=0; tt<4; tt++){
    int col = (w*4+tt)*16 + r16;                 // gate col 0..511
    #pragma unroll
    for (int kc=0; kc<8; kc++)
      Uzr[tt][kc] = *(const bf16x8*)&Ut[col*256 + kc*32 + q*8];
  }
  #pragma unroll
  for (int ct=0; ct<2; ct++){
    int col = 512 + (w*2+ct)*16 + r16;           // gate col 512..767
    #pragma unroll
    for (int kc=0; kc<8; kc++)
      Uhh[ct][kc] = *(const bf16x8*)&Ut[col*256 + kc*32 + q*8];
  }
  __syncthreads();

  #pragma unroll 1
  for (int t = 0; t < TB; t++){
    // issue this step's x_proj loads up front (latency hidden by phase-A MFMAs)
    float xa[16]; float xb[8];
    unsigned short ua[16]; unsigned short ub[8];
    #pragma unroll
    for (int tt=0; tt<4; tt++){
      int gcol = (w*4+tt)*16 + r16;
      #pragma unroll
      for (int i=0;i<4;i++){
        size_t idx = ((size_t)(b0 + q*4 + i)*TB + t)*768 + gcol;
        if (F32XP) xa[tt*4+i] = xpf[idx]; else ua[tt*4+i] = xph[idx];
      }
    }
    #pragma unroll
    for (int ct=0; ct<2; ct++){
      int gcol = 512 + (w*2+ct)*16 + r16;
      #pragma unroll
      for (int i=0;i<4;i++){
        size_t idx = ((size_t)(b0 + q*4 + i)*TB + t)*768 + gcol;
        if (F32XP) xb[ct*4+i] = xpf[idx]; else ub[ct*4+i] = xph[idx];
      }
    }

    // ---- phase A: z,r = hardsig(x + h@U[z|r]) ----
    f32x4 acc[4];
    #pragma unroll
    for (int tt=0; tt<4; tt++) acc[tt] = {0.f,0.f,0.f,0.f};
    #pragma unroll
    for (int kc=0; kc<8; kc++){
      bf16x8 a = *(const bf16x8*)&h_fb[kc*512 + lane*8];   // lane*16 bytes: conflict-free
      #pragma unroll
      for (int tt=0; tt<4; tt++)
        acc[tt] = __builtin_amdgcn_mfma_f32_16x16x32_bf16(a, Uzr[tt][kc], acc[tt], 0,0,0);
    }
    if (w < 4){                       // z tiles: gate cols 0..255
      #pragma unroll
      for (int tt=0; tt<4; tt++){
        int gcol = (w*4+tt)*16 + r16;
        #pragma unroll
        for (int i=0;i<4;i++){
          float pre = acc[tt][i] + (F32XP ? xa[tt*4+i] : bf2f(ua[tt*4+i]));
          float g = fminf(1.f, fmaxf(0.f, 0.2f*pre + 0.5f));
          z_ls[(q*4+i)*257 + gcol] = g;
        }
      }
    } else {                          // r tiles: write v = r*h (bf16, frag-order)
      #pragma unroll
      for (int tt=0; tt<4; tt++){
        int j = (w-4)*64 + tt*16 + r16;            // unit col 0..255
        #pragma unroll
        for (int i=0;i<4;i++){
          int row = q*4+i;
          float pre = acc[tt][i] + (F32XP ? xa[tt*4+i] : bf2f(ua[tt*4+i]));
          float g = fminf(1.f, fmaxf(0.f, 0.2f*pre + 0.5f));
          float v = g * h32[row*257 + j];
          v_fb[(j>>5)*512 + ((j>>3)&3)*128 + row*8 + (j&7)] = (short)f2bf(v);
        }
      }
    }
    __syncthreads();

    // ---- phase B: hh = tanh(xh + (r*h)@Uh); h = z*h + (1-z)*hh ----
    f32x4 hac[2];
    #pragma unroll
    for (int ct=0; ct<2; ct++) hac[ct] = {0.f,0.f,0.f,0.f};
    #pragma unroll
    for (int kc=0; kc<8; kc++){
      bf16x8 a = *(const bf16x8*)&v_fb[kc*512 + lane*8];
      #pragma unroll
      for (int ct=0; ct<2; ct++)
        hac[ct] = __builtin_amdgcn_mfma_f32_16x16x32_bf16(a, Uhh[ct][kc], hac[ct], 0,0,0);
    }
    #pragma unroll
    for (int ct=0; ct<2; ct++){
      int j = (w*2+ct)*16 + r16;                   // unit col 0..255
      #pragma unroll
      for (int i=0;i<4;i++){
        int row = q*4+i;
        float pre = hac[ct][i] + (F32XP ? xb[ct*4+i] : bf2f(ub[ct*4+i]));
        pre = fminf(15.f, fmaxf(-15.f, pre));
        float e  = __expf(2.f*pre);
        float hh = (e - 1.f) / (e + 1.f);
        float z  = z_ls[row*257 + j];
        float hp = h32 [row*257 + j];
        float hn = z*hp + (1.f - z)*hh;
        h32[row*257 + j] = hn;
        h_fb[(j>>5)*512 + ((j>>3)&3)*128 + row*8 + (j&7)] = (short)f2bf(hn);
      }
    }
    __syncthreads();
  }

  // write h_last (fp32)
  #pragma unroll
  for (int kkk=0; kkk<8; kkk++){
    int e = tid + kkk*512;
    int row = e >> 8, col = e & 255;
    out[(b0 + row)*256 + col] = h32[row*257 + col];
  }
}

extern "C" void kernel_launch(void* const* d_in, const int* in_sizes, int n_in,
                              void* d_out, int out_size, void* d_ws, size_t ws_size,
                              hipStream_t stream) {
  (void)in_sizes; (void)n_in; (void)out_size;
  const float* x    = (const float*)d_in[0];
  const float* Wk   = (const float*)d_in[1];
  const float* Rk   = (const float*)d_in[2];
  const float* bias = (const float*)d_in[3];
  float* out = (float*)d_out;

  const size_t XP_F32 = (size_t)64*2048*768*4;   // 402,653,184
  const size_t WT_B   = (size_t)768*256*2;       // 393,216
  bool f32xp = ws_size >= XP_F32 + 2*WT_B + 1024;

  char* p = (char*)d_ws;
  void* xproj = (void*)p;
  size_t xp_bytes = f32xp ? XP_F32 : XP_F32/2;
  unsigned short* Wt = (unsigned short*)(p + xp_bytes);
  unsigned short* Ut = (unsigned short*)(p + xp_bytes + WT_B);

  hipLaunchKernelGGL(transpose_k, dim3(1536), dim3(256), 0, stream, Wk, Rk, Wt, Ut);
  if (f32xp){
    hipLaunchKernelGGL((proj_k<1>), dim3(2048,12), dim3(256), 0, stream, x, Wt, bias, xproj);
    hipLaunchKernelGGL((gru_k<1>),  dim3(4),       dim3(512), 0, stream, xproj, Ut, out);
  } else {
    hipLaunchKernelGGL((proj_k<0>), dim3(2048,12), dim3(256), 0, stream, x, Wt, bias, xproj);
    hipLaunchKernelGGL((gru_k<0>),  dim3(4),       dim3(512), 0, stream, xproj, Ut, out);
  }
}

// Round 2
// 9321.128 us; speedup vs baseline: 1.0512x; 1.0512x over previous
//
#include <hip/hip_runtime.h>

// GRU: B=64, T=2048, D=256, U=256.
//  k0: transpose kernel(256x768 f32) -> Wt(768x256 bf16), recurrent -> Ut(768x256 bf16)
//  k1: x_proj = x @ kernel + bias (bf16 MFMA), stored bf16 T-MAJOR: [t][64][768]
//  k2: recurrence, 4 blocks x 512 thr, one block = 16 batches on one CU.
//      U resident in VGPRs as MFMA B-fragments (asm-pinned, 192 VGPRs),
//      h in LDS (fragment-order, conflict-free), x_proj loads = sgpr base + const offset.

#define TB 2048
#define NU 256
#define G3 768

typedef __attribute__((ext_vector_type(8))) short bf16x8;
typedef __attribute__((ext_vector_type(4))) float f32x4;

__device__ inline unsigned short f2bf(float f){
  union{float f; unsigned u;} v; v.f = f;
  unsigned r = v.u + 0x7fffu + ((v.u >> 16) & 1u);   // RNE
  return (unsigned short)(r >> 16);
}
__device__ inline float bf2f(unsigned short u){
  union{unsigned u; float f;} v; v.u = ((unsigned)u) << 16; return v.f;
}
__device__ inline unsigned pk2(float a, float b){
  return (unsigned)f2bf(a) | ((unsigned)f2bf(b) << 16);
}

// ---------------- k0: weight transpose to bf16 [col][k] ----------------
__global__ __launch_bounds__(256) void transpose_k(const float* __restrict__ W,
                                                   const float* __restrict__ R,
                                                   unsigned short* __restrict__ Wt,
                                                   unsigned short* __restrict__ Ut){
  int n = blockIdx.x;        // 0..1535
  int k = threadIdx.x;       // 0..255
  if (n < G3) Wt[n*NU + k] = f2bf(W[k*G3 + n]);
  else        Ut[(n-G3)*NU + k] = f2bf(R[k*G3 + (n-G3)]);
}

// ---------------- k1: projection GEMM  (M=131072, K=256, N=768) ----------------
// 64x64 tile / block, 4 waves each 32x32 (2x2 mfma 16x16x32), K chunked by 64.
// Output bf16, t-major layout: elem (b,t,col) at ((t*64+b)*768 + col).
__global__ __launch_bounds__(256) void proj_k(const float* __restrict__ x,
                                              const unsigned short* __restrict__ Wt,
                                              const float* __restrict__ bias,
                                              unsigned short* __restrict__ xproj){
  __shared__ short As[4096];
  __shared__ short Bs[4096];
  const int tid  = threadIdx.x;
  const int lane = tid & 63;
  const int wv   = tid >> 6;
  const int wr   = wv >> 1, wc = wv & 1;
  const int q    = lane >> 4, r16 = lane & 15;
  const int bm   = blockIdx.x, bn = blockIdx.y;

  f32x4 acc[2][2];
  #pragma unroll
  for (int a=0;a<2;a++)
    #pragma unroll
    for (int b=0;b<2;b++) acc[a][b] = {0.f,0.f,0.f,0.f};

  const int mA = tid >> 2, kq = tid & 3;
  const int kc32 = kq >> 1, q0 = (kq & 1) * 2;

  for (int kc0 = 0; kc0 < 256; kc0 += 64){
    {
      const float* src = x + (size_t)(bm*64 + mA)*256 + kc0 + kq*16;
      float4 f0 = *(const float4*)(src);
      float4 f1 = *(const float4*)(src+4);
      float4 f2 = *(const float4*)(src+8);
      float4 f3 = *(const float4*)(src+12);
      *(uint2*)&As[kc32*2048 + q0*512     + mA*8 + 0] = make_uint2(pk2(f0.x,f0.y), pk2(f0.z,f0.w));
      *(uint2*)&As[kc32*2048 + q0*512     + mA*8 + 4] = make_uint2(pk2(f1.x,f1.y), pk2(f1.z,f1.w));
      *(uint2*)&As[kc32*2048 + (q0+1)*512 + mA*8 + 0] = make_uint2(pk2(f2.x,f2.y), pk2(f2.z,f2.w));
      *(uint2*)&As[kc32*2048 + (q0+1)*512 + mA*8 + 4] = make_uint2(pk2(f3.x,f3.y), pk2(f3.z,f3.w));
    }
    {
      const unsigned short* srcB = Wt + (size_t)(bn*64 + mA)*256 + kc0 + kq*16;
      uint4 b0v = *(const uint4*)(srcB);
      uint4 b1v = *(const uint4*)(srcB+8);
      *(uint4*)&Bs[kc32*2048 + q0*512     + mA*8] = b0v;
      *(uint4*)&Bs[kc32*2048 + (q0+1)*512 + mA*8] = b1v;
    }
    __syncthreads();
    #pragma unroll
    for (int kk = 0; kk < 2; kk++){
      bf16x8 av[2], bv[2];
      #pragma unroll
      for (int rt=0; rt<2; rt++)
        av[rt] = *(const bf16x8*)&As[kk*2048 + q*512 + (wr*32+rt*16+r16)*8];
      #pragma unroll
      for (int ct=0; ct<2; ct++)
        bv[ct] = *(const bf16x8*)&Bs[kk*2048 + q*512 + (wc*32+ct*16+r16)*8];
      #pragma unroll
      for (int rt=0; rt<2; rt++)
        #pragma unroll
        for (int ct=0; ct<2; ct++)
          acc[rt][ct] = __builtin_amdgcn_mfma_f32_16x16x32_bf16(av[rt], bv[ct], acc[rt][ct], 0,0,0);
    }
    __syncthreads();
  }
  #pragma unroll
  for (int rt=0; rt<2; rt++){
    #pragma unroll
    for (int ct=0; ct<2; ct++){
      int colg = bn*64 + wc*32 + ct*16 + r16;
      float bb = bias[colg];
      #pragma unroll
      for (int i=0;i<4;i++){
        int rowg = bm*64 + wr*32 + rt*16 + q*4 + i;   // = b*2048 + t
        int b = rowg >> 11, t = rowg & 2047;
        float v = acc[rt][ct][i] + bb;
        xproj[(size_t)(t*64 + b)*768 + colg] = f2bf(v);
      }
    }
  }
}

// ---------------- k2: recurrence ----------------
// 4 blocks x 512 threads (8 waves). Block g owns batches g*16..g*16+15.
// Wave w: phase A col-tiles {4w..4w+3} (gate cols 0..511), phase B h-tiles {2w,2w+1}.
#define PIN(v) asm volatile("" : "+v"(v))
__global__ __launch_bounds__(512, 1) void gru_k(const unsigned short* __restrict__ xp,
                                                const unsigned short* __restrict__ Ut,
                                                float* __restrict__ out){
  __shared__ short h_fb[4096];      // h bf16, fragment-order [kc][q][row][8]
  __shared__ short v_fb[4096];      // (r*h) bf16, same order
  __shared__ float z_ls[16*258];    // z gate fp32, stride 258: bank=(2row+col)%32, <=2-way
  __shared__ float h32 [16*258];    // h fp32 master

  const int tid  = threadIdx.x;
  const int w    = tid >> 6;        // wave 0..7
  const int lane = tid & 63;
  const int q    = lane >> 4, r16 = lane & 15;
  const int b0   = blockIdx.x * 16;

  for (int i = tid; i < 4096;   i += 512) h_fb[i] = 0;
  for (int i = tid; i < 16*258; i += 512) h32[i]  = 0.f;

  // one-time U fragment load -> registers, pinned so the compiler cannot
  // rematerialize the global loads inside the t-loop (R1: VGPR=128 + L2 reload = 9.4ms)
  bf16x8 Uzr[4][8];     // 128 VGPRs: gate cols (w*4+tt)*16+r16, tt=0..3
  bf16x8 Uhh[2][8];     //  64 VGPRs: gate cols 512+(w*2+ct)*16+r16
  #pragma unroll
  for (int tt=0; tt<4; tt++){
    int col = (w*4+tt)*16 + r16;
    #pragma unroll
    for (int kc=0; kc<8; kc++)
      Uzr[tt][kc] = *(const bf16x8*)&Ut[col*256 + kc*32 + q*8];
  }
  #pragma unroll
  for (int ct=0; ct<2; ct++){
    int col = 512 + (w*2+ct)*16 + r16;
    #pragma unroll
    for (int kc=0; kc<8; kc++)
      Uhh[ct][kc] = *(const bf16x8*)&Ut[col*256 + kc*32 + q*8];
  }
  #pragma unroll
  for (int tt=0; tt<4; tt++)
    #pragma unroll
    for (int kc=0; kc<8; kc++) PIN(Uzr[tt][kc]);
  #pragma unroll
  for (int ct=0; ct<2; ct++)
    #pragma unroll
    for (int kc=0; kc<8; kc++) PIN(Uhh[ct][kc]);

  __syncthreads();

  // x_proj t-major: step t block at xp + t*49152; per-thread offsets loop-invariant
  const int offA = (b0 + q*4)*768 + w*64 + r16;          // + i*768 + tt*16
  const int offB = (b0 + q*4)*768 + 512 + w*32 + r16;    // + i*768 + ct*16
  const unsigned short* xt = xp;

  #pragma unroll 1
  for (int t = 0; t < TB; t++){
    // issue this step's x_proj loads up front (phase-A MFMAs hide latency)
    unsigned short ua[16]; unsigned short ub[8];
    #pragma unroll
    for (int tt=0; tt<4; tt++)
      #pragma unroll
      for (int i=0;i<4;i++)
        ua[tt*4+i] = xt[offA + i*768 + tt*16];
    #pragma unroll
    for (int ct=0; ct<2; ct++)
      #pragma unroll
      for (int i=0;i<4;i++)
        ub[ct*4+i] = xt[offB + i*768 + ct*16];

    // ---- phase A: z,r = hardsig(x + h@U[z|r]) ----
    f32x4 acc[4];
    #pragma unroll
    for (int tt=0; tt<4; tt++) acc[tt] = {0.f,0.f,0.f,0.f};
    #pragma unroll
    for (int kc=0; kc<8; kc++){
      bf16x8 a = *(const bf16x8*)&h_fb[kc*512 + lane*8];   // lane*16B: conflict-free
      #pragma unroll
      for (int tt=0; tt<4; tt++)
        acc[tt] = __builtin_amdgcn_mfma_f32_16x16x32_bf16(a, Uzr[tt][kc], acc[tt], 0,0,0);
    }
    if (w < 4){                       // z tiles: gate cols 0..255
      #pragma unroll
      for (int tt=0; tt<4; tt++){
        int gcol = w*64 + tt*16 + r16;
        #pragma unroll
        for (int i=0;i<4;i++){
          float pre = acc[tt][i] + bf2f(ua[tt*4+i]);
          float g = fminf(1.f, fmaxf(0.f, 0.2f*pre + 0.5f));
          z_ls[(q*4+i)*258 + gcol] = g;
        }
      }
    } else {                          // r tiles: write v = r*h (bf16, frag-order)
      #pragma unroll
      for (int tt=0; tt<4; tt++){
        int j = (w-4)*64 + tt*16 + r16;            // unit col 0..255
        #pragma unroll
        for (int i=0;i<4;i++){
          int row = q*4+i;
          float pre = acc[tt][i] + bf2f(ua[tt*4+i]);
          float g = fminf(1.f, fmaxf(0.f, 0.2f*pre + 0.5f));
          float v = g * h32[row*258 + j];
          v_fb[(j>>5)*512 + ((j>>3)&3)*128 + row*8 + (j&7)] = (short)f2bf(v);
        }
      }
    }
    __syncthreads();

    // ---- phase B: hh = tanh(xh + (r*h)@Uh); h = z*h + (1-z)*hh ----
    f32x4 hac[2];
    #pragma unroll
    for (int ct=0; ct<2; ct++) hac[ct] = {0.f,0.f,0.f,0.f};
    #pragma unroll
    for (int kc=0; kc<8; kc++){
      bf16x8 a = *(const bf16x8*)&v_fb[kc*512 + lane*8];
      #pragma unroll
      for (int ct=0; ct<2; ct++)
        hac[ct] = __builtin_amdgcn_mfma_f32_16x16x32_bf16(a, Uhh[ct][kc], hac[ct], 0,0,0);
    }
    #pragma unroll
    for (int ct=0; ct<2; ct++){
      int j = (w*2+ct)*16 + r16;                   // unit col 0..255
      #pragma unroll
      for (int i=0;i<4;i++){
        int row = q*4+i;
        float pre = hac[ct][i] + bf2f(ub[ct*4+i]);
        pre = fminf(15.f, fmaxf(-15.f, pre));
        float e  = __expf(2.f*pre);
        float hh = 1.f - 2.f*__builtin_amdgcn_rcpf(e + 1.f);
        float z  = z_ls[row*258 + j];
        float hp = h32 [row*258 + j];
        float hn = z*hp + (1.f - z)*hh;
        h32[row*258 + j] = hn;
        h_fb[(j>>5)*512 + ((j>>3)&3)*128 + row*8 + (j&7)] = (short)f2bf(hn);
      }
    }
    __syncthreads();
    xt += 64*768;
  }

  // write h_last (fp32)
  #pragma unroll
  for (int kkk=0; kkk<8; kkk++){
    int e = tid + kkk*512;
    int row = e >> 8, col = e & 255;
    out[(b0 + row)*256 + col] = h32[row*258 + col];
  }
}

extern "C" void kernel_launch(void* const* d_in, const int* in_sizes, int n_in,
                              void* d_out, int out_size, void* d_ws, size_t ws_size,
                              hipStream_t stream) {
  (void)in_sizes; (void)n_in; (void)out_size; (void)ws_size;
  const float* x    = (const float*)d_in[0];
  const float* Wk   = (const float*)d_in[1];
  const float* Rk   = (const float*)d_in[2];
  const float* bias = (const float*)d_in[3];
  float* out = (float*)d_out;

  const size_t XP_B = (size_t)64*2048*768*2;     // 201,326,592 (bf16, t-major)
  const size_t WT_B = (size_t)768*256*2;         // 393,216

  char* p = (char*)d_ws;
  unsigned short* xproj = (unsigned short*)p;
  unsigned short* Wt = (unsigned short*)(p + XP_B);
  unsigned short* Ut = (unsigned short*)(p + XP_B + WT_B);

  hipLaunchKernelGGL(transpose_k, dim3(1536),    dim3(256), 0, stream, Wk, Rk, Wt, Ut);
  hipLaunchKernelGGL(proj_k,      dim3(2048,12), dim3(256), 0, stream, x, Wt, bias, xproj);
  hipLaunchKernelGGL(gru_k,       dim3(4),       dim3(512), 0, stream, xproj, Ut, out);
}

// Round 4
// 4593.005 us; speedup vs baseline: 2.1334x; 2.0294x over previous
//
#include <hip/hip_runtime.h>

// GRU: B=64, T=2048, D=256, U=256.
//  k0: transpose weights -> bf16 [col][k]
//  k1: proj GEMM -> recurrence-native x layout:
//      XA[t][g][w][lane] = 2 uint4: slot0 = xz[8] (written by bn<4 blocks),
//                                   slot1 = xr[8] (written by bn 4..7 blocks)
//      XB[t][g][w][lane] = 1 uint4: xh[8]        (written by bn 8..11 blocks)
//      (R3 bug: z and r blocks both stored full 16-short records, each with the
//       other half uninitialized -> race. Now disjoint uint4 stores.)
//  k2: recurrence, 4 blocks x 512 thr. Wave w owns gate cols [w*32,w*32+32) for
//      z, r, h. U in 192 VGPRs; z (bf16-packed) + h_prev in regs; only h and
//      (r*h) fragments round-trip LDS.

#define TB 2048
#define NU 256
#define G3 768

typedef __attribute__((ext_vector_type(8))) short bf16x8;
typedef __attribute__((ext_vector_type(4))) float f32x4;

__device__ inline unsigned short f2bf(float f){
  union{float f; unsigned u;} v; v.f = f;
  unsigned r = v.u + 0x7fffu + ((v.u >> 16) & 1u);   // RNE
  return (unsigned short)(r >> 16);
}
__device__ inline unsigned pk2(float a, float b){
  return (unsigned)f2bf(a) | ((unsigned)f2bf(b) << 16);
}
__device__ inline float bflo(unsigned u){
  union{unsigned u; float f;} v; v.u = u << 16; return v.f;
}
__device__ inline float bfhi(unsigned u){
  union{unsigned u; float f;} v; v.u = u & 0xffff0000u; return v.f;
}

// ---------------- k0: weight transpose to bf16 [col][k] ----------------
__global__ __launch_bounds__(256) void transpose_k(const float* __restrict__ W,
                                                   const float* __restrict__ R,
                                                   unsigned short* __restrict__ Wt,
                                                   unsigned short* __restrict__ Ut){
  int n = blockIdx.x;        // 0..1535
  int k = threadIdx.x;       // 0..255
  if (n < G3) Wt[n*NU + k] = f2bf(W[k*G3 + n]);
  else        Ut[(n-G3)*NU + k] = f2bf(R[k*G3 + (n-G3)]);
}

// ---------------- k1: projection GEMM ----------------
// Block = (t = blockIdx.x, 64-gate-col chunk bn = blockIdx.y) x all 64 batches.
__global__ __launch_bounds__(256) void proj_k(const float* __restrict__ x,
                                              const unsigned short* __restrict__ Wt,
                                              const float* __restrict__ bias,
                                              unsigned short* __restrict__ XA,
                                              unsigned short* __restrict__ XB){
  __shared__ short As[4096];
  __shared__ short Bs[4096];
  __shared__ short St[4096];        // compact [chunk 0..7][lane 0..63][8]
  const int tid  = threadIdx.x;
  const int lane = tid & 63;
  const int wv   = tid >> 6;
  const int wr   = wv >> 1, wc = wv & 1;
  const int q    = lane >> 4, r16 = lane & 15;
  const int tm   = blockIdx.x;      // time step
  const int bn   = blockIdx.y;      // 0..11 gate-col chunk

  f32x4 acc[2][2];
  #pragma unroll
  for (int a=0;a<2;a++)
    #pragma unroll
    for (int b=0;b<2;b++) acc[a][b] = {0.f,0.f,0.f,0.f};

  const int mA = tid >> 2, kq = tid & 3;
  const int kc32 = kq >> 1, q0 = (kq & 1) * 2;

  for (int kc0 = 0; kc0 < 256; kc0 += 64){
    {
      const float* src = x + (size_t)mA*(2048*256) + (size_t)tm*256 + kc0 + kq*16;
      float4 f0 = *(const float4*)(src);
      float4 f1 = *(const float4*)(src+4);
      float4 f2 = *(const float4*)(src+8);
      float4 f3 = *(const float4*)(src+12);
      *(uint2*)&As[kc32*2048 + q0*512     + mA*8 + 0] = make_uint2(pk2(f0.x,f0.y), pk2(f0.z,f0.w));
      *(uint2*)&As[kc32*2048 + q0*512     + mA*8 + 4] = make_uint2(pk2(f1.x,f1.y), pk2(f1.z,f1.w));
      *(uint2*)&As[kc32*2048 + (q0+1)*512 + mA*8 + 0] = make_uint2(pk2(f2.x,f2.y), pk2(f2.z,f2.w));
      *(uint2*)&As[kc32*2048 + (q0+1)*512 + mA*8 + 4] = make_uint2(pk2(f3.x,f3.y), pk2(f3.z,f3.w));
    }
    {
      const unsigned short* srcB = Wt + (size_t)(bn*64 + mA)*256 + kc0 + kq*16;
      uint4 b0v = *(const uint4*)(srcB);
      uint4 b1v = *(const uint4*)(srcB+8);
      *(uint4*)&Bs[kc32*2048 + q0*512     + mA*8] = b0v;
      *(uint4*)&Bs[kc32*2048 + (q0+1)*512 + mA*8] = b1v;
    }
    __syncthreads();
    #pragma unroll
    for (int kk = 0; kk < 2; kk++){
      bf16x8 av[2], bv[2];
      #pragma unroll
      for (int rt=0; rt<2; rt++)
        av[rt] = *(const bf16x8*)&As[kk*2048 + q*512 + (wr*32+rt*16+r16)*8];
      #pragma unroll
      for (int ct=0; ct<2; ct++)
        bv[ct] = *(const bf16x8*)&Bs[kk*2048 + q*512 + (wc*32+ct*16+r16)*8];
      #pragma unroll
      for (int rt=0; rt<2; rt++)
        #pragma unroll
        for (int ct=0; ct<2; ct++)
          acc[rt][ct] = __builtin_amdgcn_mfma_f32_16x16x32_bf16(av[rt], bv[ct], acc[rt][ct], 0,0,0);
    }
    __syncthreads();
  }

  // epilogue: +bias, stage compact recurrence-native order in St
  const int csub = (bn < 4) ? 0 : (bn < 8 ? 256 : 512);
  #pragma unroll
  for (int rt=0; rt<2; rt++){
    #pragma unroll
    for (int ct=0; ct<2; ct++){
      int colg = bn*64 + wc*32 + ct*16 + r16;
      float bb = bias[colg];
      int c = colg - csub;                 // 0..255 within z / r / h
      int wi = (c >> 5) & 1, tt2 = (c >> 4) & 1, r16g = c & 15;
      #pragma unroll
      for (int i=0;i<4;i++){
        int b = wr*32 + rt*16 + q*4 + i;   // batch
        int gg = b >> 4, lb = b & 15;
        int lane_ = (lb >> 2)*16 + r16g, ii = lb & 3;
        St[(gg*2+wi)*512 + lane_*8 + tt2*4 + ii] = (short)f2bf(acc[rt][ct][i] + bb);
      }
    }
  }
  __syncthreads();

  // disjoint coalesced stores: z -> XA slot 0, r -> XA slot 1, h -> XB
  #pragma unroll
  for (int it=0; it<2; it++){
    int idx = tid + it*256;            // 0..511
    int chunk = idx >> 6, within = idx & 63;
    int gg = chunk >> 1, wi = chunk & 1;
    int w_ = (bn & 3)*2 + wi;
    uint4 val = *(const uint4*)&St[chunk*512 + within*8];
    if (bn < 8){
      int sel = (bn < 4) ? 0 : 1;
      *((uint4*)XA + ((((size_t)tm*4+gg)*8 + w_)*64 + within)*2 + sel) = val;
    } else {
      *((uint4*)XB + (((size_t)tm*4+gg)*8 + w_)*64 + within) = val;
    }
  }
}

// ---------------- k2: recurrence ----------------
__global__ __launch_bounds__(512, 2) void gru_k(const unsigned short* __restrict__ XA,
                                                const unsigned short* __restrict__ XB,
                                                const unsigned short* __restrict__ Ut,
                                                float* __restrict__ out){
  __shared__ short h_fb[4096];      // h   bf16, frag-order [kc][qk][row][8]
  __shared__ short v_fb[4096];      // r*h bf16, same order

  const int tid  = threadIdx.x;
  const int w    = tid >> 6;        // wave 0..7 owns unit cols [w*32, w*32+32)
  const int lane = tid & 63;
  const int q    = lane >> 4, r16 = lane & 15;
  const int g    = blockIdx.x;
  const int b0   = g * 16;

  for (int i = tid; i < 4096; i += 512) h_fb[i] = 0;

  // one-time U fragment load -> 192 VGPRs
  bf16x8 Uz[2][8], Ur[2][8], Uh[2][8];
  #pragma unroll
  for (int tt=0; tt<2; tt++){
    int cz = w*32 + tt*16 + r16;
    #pragma unroll
    for (int kc=0; kc<8; kc++){
      Uz[tt][kc] = *(const bf16x8*)&Ut[(cz      )*256 + kc*32 + q*8];
      Ur[tt][kc] = *(const bf16x8*)&Ut[(cz + 256)*256 + kc*32 + q*8];
      Uh[tt][kc] = *(const bf16x8*)&Ut[(cz + 512)*256 + kc*32 + q*8];
    }
  }

  float hprev[2][4] = {{0.f,0.f,0.f,0.f},{0.f,0.f,0.f,0.f}};
  unsigned zpk[4];

  const uint4* pA = (const uint4*)XA + ((size_t)(g*8+w)*64 + lane)*2;
  const uint4* pB = (const uint4*)XB + ((size_t)(g*8+w)*64 + lane);

  __syncthreads();

  #pragma unroll 1
  for (int t = 0; t < TB; t++){
    uint4 xa0 = pA[0], xa1 = pA[1];
    uint4 xb0 = pB[0];
    unsigned xw[8] = {xa0.x,xa0.y,xa0.z,xa0.w,xa1.x,xa1.y,xa1.z,xa1.w};

    // ---- phase A: z,r for own 32 gate cols ----
    f32x4 az[2] = {{0.f,0.f,0.f,0.f},{0.f,0.f,0.f,0.f}};
    f32x4 ar[2] = {{0.f,0.f,0.f,0.f},{0.f,0.f,0.f,0.f}};
    #pragma unroll
    for (int kc=0; kc<8; kc++){
      bf16x8 a = *(const bf16x8*)&h_fb[kc*512 + lane*8];   // lane*16B: conflict-free
      az[0] = __builtin_amdgcn_mfma_f32_16x16x32_bf16(a, Uz[0][kc], az[0], 0,0,0);
      az[1] = __builtin_amdgcn_mfma_f32_16x16x32_bf16(a, Uz[1][kc], az[1], 0,0,0);
      ar[0] = __builtin_amdgcn_mfma_f32_16x16x32_bf16(a, Ur[0][kc], ar[0], 0,0,0);
      ar[1] = __builtin_amdgcn_mfma_f32_16x16x32_bf16(a, Ur[1][kc], ar[1], 0,0,0);
    }
    #pragma unroll
    for (int tt=0; tt<2; tt++){
      float z4[4];
      #pragma unroll
      for (int i=0;i<4;i++){
        int s = tt*4 + i;
        float xz = (s&1) ? bfhi(xw[s>>1]) : bflo(xw[s>>1]);
        z4[i] = fminf(1.f, fmaxf(0.f, 0.2f*(az[tt][i] + xz) + 0.5f));
        int sr = 8 + tt*4 + i;
        float xr = (sr&1) ? bfhi(xw[sr>>1]) : bflo(xw[sr>>1]);
        float r = fminf(1.f, fmaxf(0.f, 0.2f*(ar[tt][i] + xr) + 0.5f));
        float v = r * hprev[tt][i];
        // unit col j = w*32+tt*16+r16 -> frag addr
        v_fb[w*512 + (tt*2 + (r16>>3))*128 + (q*4+i)*8 + (r16&7)] = (short)f2bf(v);
      }
      zpk[tt*2+0] = pk2(z4[0], z4[1]);
      zpk[tt*2+1] = pk2(z4[2], z4[3]);
    }
    __syncthreads();

    // ---- phase B: hh = tanh(xh + (r*h)@Uh); h = z*h + (1-z)*hh ----
    f32x4 ah[2] = {{0.f,0.f,0.f,0.f},{0.f,0.f,0.f,0.f}};
    #pragma unroll
    for (int kc=0; kc<8; kc++){
      bf16x8 a = *(const bf16x8*)&v_fb[kc*512 + lane*8];
      ah[0] = __builtin_amdgcn_mfma_f32_16x16x32_bf16(a, Uh[0][kc], ah[0], 0,0,0);
      ah[1] = __builtin_amdgcn_mfma_f32_16x16x32_bf16(a, Uh[1][kc], ah[1], 0,0,0);
    }
    unsigned xwb[4] = {xb0.x,xb0.y,xb0.z,xb0.w};
    #pragma unroll
    for (int ct=0; ct<2; ct++){
      #pragma unroll
      for (int i=0;i<4;i++){
        int s = ct*4 + i;
        float xh = (s&1) ? bfhi(xwb[s>>1]) : bflo(xwb[s>>1]);
        float pre = ah[ct][i] + xh;
        pre = fminf(15.f, fmaxf(-15.f, pre));
        float e  = __expf(2.f*pre);
        float hh = 1.f - 2.f*__builtin_amdgcn_rcpf(e + 1.f);
        unsigned zw = zpk[ct*2 + (i>>1)];
        float z = (i&1) ? bfhi(zw) : bflo(zw);
        float hn = z*hprev[ct][i] + (1.f - z)*hh;
        hprev[ct][i] = hn;
        h_fb[w*512 + (ct*2 + (r16>>3))*128 + (q*4+i)*8 + (r16&7)] = (short)f2bf(hn);
      }
    }
    __syncthreads();
    pA += 4096;    // 32768 shorts / t
    pB += 2048;    // 16384 shorts / t
  }

  // h_last from registers
  #pragma unroll
  for (int ct=0; ct<2; ct++)
    #pragma unroll
    for (int i=0;i<4;i++)
      out[(size_t)(b0 + q*4 + i)*256 + w*32 + ct*16 + r16] = hprev[ct][i];
}

extern "C" void kernel_launch(void* const* d_in, const int* in_sizes, int n_in,
                              void* d_out, int out_size, void* d_ws, size_t ws_size,
                              hipStream_t stream) {
  (void)in_sizes; (void)n_in; (void)out_size; (void)ws_size;
  const float* x    = (const float*)d_in[0];
  const float* Wk   = (const float*)d_in[1];
  const float* Rk   = (const float*)d_in[2];
  const float* bias = (const float*)d_in[3];
  float* out = (float*)d_out;

  unsigned short* XA = (unsigned short*)d_ws;                 // 2048*32768 shorts
  unsigned short* XB = XA + (size_t)2048*32768;               // 2048*16384 shorts
  unsigned short* Wt = XB + (size_t)2048*16384;               // 768*256
  unsigned short* Ut = Wt + (size_t)768*256;                  // 768*256

  hipLaunchKernelGGL(transpose_k, dim3(1536),    dim3(256), 0, stream, Wk, Rk, Wt, Ut);
  hipLaunchKernelGGL(proj_k,      dim3(2048,12), dim3(256), 0, stream, x, Wt, bias, XA, XB);
  hipLaunchKernelGGL(gru_k,       dim3(4),       dim3(512), 0, stream, XA, XB, Ut, out);
}